// Round 8
// baseline (59.230 us; speedup 1.0000x reference)
//
#include <hip/hip_runtime.h>
#include <math.h>

#define VOXEL 32
#define NCELL (VOXEL * VOXEL)  // 1024 cells per batch
#define CHUNK 16               // features per block
#define BT 1024                // threads per block
#define PAD 17                 // padded words per cell (odd -> conflict-free strided reads)
#define MAXN 8192              // max points per batch for fused path (32 KB cell cache)

// Order-preserving f32 <-> u32 encoding: unsigned compare == float compare.
// enc(any real float) > 0, so 0 marks "untouched".
__device__ __forceinline__ unsigned int enc_f32(float f) {
    unsigned int u = __float_as_uint(f);
    return (u & 0x80000000u) ? ~u : (u | 0x80000000u);
}
__device__ __forceinline__ float dec_f32(unsigned int u) {
    if (u == 0u) return 0.0f;
    return __uint_as_float((u & 0x80000000u) ? (u ^ 0x80000000u) : ~u);
}

// One block per (batch, 16-feature chunk). Phase 0: precompute each point's
// padded cell offset into LDS. Phase 1: thread (pi, fi) streams points
// pi, pi+64, ... doing {1 dword load, 1 LDS atomicMax} per iter - iterations
// independent, unroll-4 keeps 4 loads in flight. acc[cell][PAD=17] spreads a
// wave's 4cells x 16fi across banks (~2-way, free). Phase 2: thread t decodes
// cell t and writes 64 B.
__global__ void __launch_bounds__(BT)
voxelize_fused2(const float* __restrict__ feat,
                const float* __restrict__ coords,
                float* __restrict__ out, int N, int F) {
    __shared__ unsigned int acc[NCELL * PAD];  // 68 KB
    __shared__ int cells[MAXN];                // 32 KB (padded cell offsets)

    const int nchunks = F / CHUNK;
    const int b     = blockIdx.x / nchunks;
    const int chunk = blockIdx.x % nchunks;
    const int t     = threadIdx.x;

#pragma unroll
    for (int i = t; i < NCELL * PAD; i += BT) acc[i] = 0u;

    // Phase 0: cells[p] = (gy*32+gx)*PAD, coalesced float2 coord reads.
    const float2* cb = (const float2*)(coords + (size_t)b * N * 2);
    for (int p = t; p < N; p += BT) {
        const float2 xy = cb[p];
        int gx = (int)(xy.x * (float)(VOXEL - 1));  // trunc == astype(int32)
        int gy = (int)(xy.y * (float)(VOXEL - 1));
        gx = min(max(gx, 0), VOXEL - 1);
        gy = min(max(gy, 0), VOXEL - 1);
        cells[p] = (gy * VOXEL + gx) * PAD;
    }
    __syncthreads();

    // Phase 1: stream features. 64 consecutive points per iteration across
    // the block; each point's 16 chunk-features handled by 16 lanes (64 B
    // contiguous global segment per point).
    const int fi = t & (CHUNK - 1);
    const int pi = t >> 4;  // 0..63
    const float* fb = feat + (size_t)b * N * F + (size_t)chunk * CHUNK + fi;

#pragma unroll 4
    for (int p = pi; p < N; p += BT / CHUNK) {
        const unsigned int v = enc_f32(fb[(size_t)p * F]);
        atomicMax(&acc[cells[p] + fi], v);
    }
    __syncthreads();

    // Phase 2: thread t owns cell t (BT == NCELL).
    float r[CHUNK];
#pragma unroll
    for (int k = 0; k < CHUNK; ++k) r[k] = dec_f32(acc[t * PAD + k]);

    float* dst = out + ((size_t)b * NCELL + t) * F + (size_t)chunk * CHUNK;
#pragma unroll
    for (int k = 0; k < CHUNK / 4; ++k)
        ((float4*)dst)[k] = make_float4(r[4 * k + 0], r[4 * k + 1],
                                        r[4 * k + 2], r[4 * k + 3]);
}

// ---------- fallback path (round-1 atomic version, any F%4==0) ----------

__device__ __forceinline__ int cell_of(const float* __restrict__ coords, int point, int N) {
    float x = coords[(size_t)point * 2 + 0];
    float y = coords[(size_t)point * 2 + 1];
    int gx = (int)(x * (float)(VOXEL - 1));
    int gy = (int)(y * (float)(VOXEL - 1));
    gx = min(max(gx, 0), VOXEL - 1);
    gy = min(max(gy, 0), VOXEL - 1);
    int b = point / N;
    return b * NCELL + gy * VOXEL + gx;
}

__global__ void voxel_scatter_max(const float* __restrict__ feat,
                                  const float* __restrict__ coords,
                                  unsigned int* __restrict__ out,
                                  int BN, int N, int F) {
    int gid   = blockIdx.x * blockDim.x + threadIdx.x;
    int point = gid / (F / 4);
    int fi    = gid % (F / 4);
    if (point >= BN) return;
    int idx = cell_of(coords, point, N);
    const float4 v = *(const float4*)(feat + (size_t)point * F + fi * 4);
    unsigned int* o = out + (size_t)idx * F + fi * 4;
    atomicMax(o + 0, enc_f32(v.x));
    atomicMax(o + 1, enc_f32(v.y));
    atomicMax(o + 2, enc_f32(v.z));
    atomicMax(o + 3, enc_f32(v.w));
}

__global__ void voxel_decode(unsigned int* __restrict__ out, int n4) {
    int i = blockIdx.x * blockDim.x + threadIdx.x;
    if (i >= n4) return;
    uint4 u = ((const uint4*)out)[i];
    float4 f;
    f.x = dec_f32(u.x); f.y = dec_f32(u.y);
    f.z = dec_f32(u.z); f.w = dec_f32(u.w);
    ((float4*)out)[i] = f;
}

// ---------- launch ----------

extern "C" void kernel_launch(void* const* d_in, const int* in_sizes, int n_in,
                              void* d_out, int out_size, void* d_ws, size_t ws_size,
                              hipStream_t stream) {
    const float* feat   = (const float*)d_in[0];
    const float* coords = (const float*)d_in[1];
    float* out          = (float*)d_out;

    const int BN = in_sizes[1] / 2;             // 131072 points
    const int F  = in_sizes[0] / BN;            // 256
    const int B  = out_size / (NCELL * F);      // 16
    const int N  = BN / B;                      // 8192

    const bool fast_ok = (F % CHUNK == 0) && (F % 4 == 0) && (N <= MAXN) &&
                         (B * N == BN) && (B * NCELL * F == out_size);

    if (fast_ok) {
        const int nblocks = B * (F / CHUNK);  // 256 for the bench shape
        voxelize_fused2<<<nblocks, BT, 0, stream>>>(feat, coords, out, N, F);
    } else {
        hipMemsetAsync(d_out, 0, (size_t)out_size * sizeof(float), stream);
        int threads = BN * (F / 4);
        voxel_scatter_max<<<(threads + 255) / 256, 256, 0, stream>>>(feat, coords,
                                                                     (unsigned int*)d_out,
                                                                     BN, N, F);
        int n4 = out_size / 4;
        voxel_decode<<<(n4 + 255) / 256, 256, 0, stream>>>((unsigned int*)d_out, n4);
    }
}

// Round 9
// 39.208 us; speedup vs baseline: 1.5107x; 1.5107x over previous
//
#include <hip/hip_runtime.h>
#include <math.h>

#define VOXEL 32
#define NCELL (VOXEL * VOXEL)  // 1024 cells per batch
#define CAP 64                 // bucket capacity; Poisson(8) => P(>=64) ~ 1e-38
#define OVF_MAX 4096

// ---------- helpers ----------

__device__ __forceinline__ int cell_of(const float* __restrict__ coords, int point, int N) {
    float x = coords[(size_t)point * 2 + 0];
    float y = coords[(size_t)point * 2 + 1];
    int gx = (int)(x * (float)(VOXEL - 1));  // trunc == astype(int32) for x>=0
    int gy = (int)(y * (float)(VOXEL - 1));
    gx = min(max(gx, 0), VOXEL - 1);
    gy = min(max(gy, 0), VOXEL - 1);
    int b = point / N;
    return b * NCELL + gy * VOXEL + gx;
}

__device__ __forceinline__ void fmax2(float2& m, const float2 v) {
    m.x = fmaxf(m.x, v.x); m.y = fmaxf(m.y, v.y);
}

// ---------- 3-dispatch binned path ----------

__global__ void scatter_bucket(const float* __restrict__ coords,
                               unsigned int* __restrict__ counts,
                               unsigned int* __restrict__ sorted,
                               unsigned int* __restrict__ ovf_cnt,
                               unsigned int* __restrict__ ovf_list,
                               int BN, int N) {
    int p = blockIdx.x * blockDim.x + threadIdx.x;
    if (p >= BN) return;
    const float2 xy = ((const float2*)coords)[p];
    int gx = (int)(xy.x * (float)(VOXEL - 1));
    int gy = (int)(xy.y * (float)(VOXEL - 1));
    gx = min(max(gx, 0), VOXEL - 1);
    gy = min(max(gy, 0), VOXEL - 1);
    int c = (p / N) * NCELL + gy * VOXEL + gx;
    unsigned int pos = atomicAdd(&counts[c], 1u);
    if (pos < CAP) {
        sorted[(size_t)c * CAP + pos] = (unsigned int)p;
    } else {
        unsigned int o = atomicAdd(ovf_cnt, 1u);
        if (o < OVF_MAX) ovf_list[o] = (unsigned int)p;
    }
}

// Two waves per cell (feature-split): wave half h owns features
// [h*F/2 + lane*2, +2). 64 lanes x 8B = 512B contiguous per row segment.
// 8-wide batches with clamped index: 8 independent loads in flight; padded
// slots re-read the last row (L1 hit). Overflow folded in (cold path).
__global__ void __launch_bounds__(256)
gather_kernel(const float* __restrict__ feat,
              const float* __restrict__ coords,
              const unsigned int* __restrict__ sorted,
              const unsigned int* __restrict__ counts,
              const unsigned int* __restrict__ ovf_cnt,
              const unsigned int* __restrict__ ovf_list,
              float* __restrict__ out, int N, int F) {
    const int wave = threadIdx.x >> 6;          // 0..3
    const int lane = threadIdx.x & 63;
    const int gw   = blockIdx.x * 4 + wave;     // global wave id
    const int cell = gw >> 1;
    const int half = gw & 1;
    const int foff = half * (F / 2) + lane * 2; // this wave-lane's feature offset

    const unsigned int raw = counts[cell];
    const int cnt = (int)min(raw, (unsigned int)CAP);
    const size_t cb = (size_t)cell * CAP;
    unsigned int pid_l = (lane < cnt) ? sorted[cb + lane] : 0u;

    float2 m = make_float2(-INFINITY, -INFINITY);
    const int e = cnt - 1;
    for (int j = 0; j < cnt; j += 8) {
        const int p0 = __shfl((int)pid_l, min(j + 0, e));
        const int p1 = __shfl((int)pid_l, min(j + 1, e));
        const int p2 = __shfl((int)pid_l, min(j + 2, e));
        const int p3 = __shfl((int)pid_l, min(j + 3, e));
        const int p4 = __shfl((int)pid_l, min(j + 4, e));
        const int p5 = __shfl((int)pid_l, min(j + 5, e));
        const int p6 = __shfl((int)pid_l, min(j + 6, e));
        const int p7 = __shfl((int)pid_l, min(j + 7, e));
        const float2 v0 = *(const float2*)(feat + (size_t)p0 * F + foff);
        const float2 v1 = *(const float2*)(feat + (size_t)p1 * F + foff);
        const float2 v2 = *(const float2*)(feat + (size_t)p2 * F + foff);
        const float2 v3 = *(const float2*)(feat + (size_t)p3 * F + foff);
        const float2 v4 = *(const float2*)(feat + (size_t)p4 * F + foff);
        const float2 v5 = *(const float2*)(feat + (size_t)p5 * F + foff);
        const float2 v6 = *(const float2*)(feat + (size_t)p6 * F + foff);
        const float2 v7 = *(const float2*)(feat + (size_t)p7 * F + foff);
        fmax2(m, v0); fmax2(m, v1); fmax2(m, v2); fmax2(m, v3);
        fmax2(m, v4); fmax2(m, v5); fmax2(m, v6); fmax2(m, v7);
    }

    // Cold path: points that spilled past CAP anywhere in the grid.
    const unsigned int novf = *ovf_cnt;
    if (novf != 0u) {
        const int n = (int)min(novf, (unsigned int)OVF_MAX);
        for (int i = 0; i < n; ++i) {
            const unsigned int p = ovf_list[i];
            if (cell_of(coords, (int)p, N) == cell) {
                const float2 v = *(const float2*)(feat + (size_t)p * F + foff);
                fmax2(m, v);
            }
        }
    }

    if (raw == 0u) m = make_float2(0.f, 0.f);
    *(float2*)(out + (size_t)cell * F + foff) = m;
}

// ---------- last-resort fallback (round-1 atomic path, any F%4==0) ----------

__device__ __forceinline__ unsigned int enc_f32(float f) {
    unsigned int u = __float_as_uint(f);
    return (u & 0x80000000u) ? ~u : (u | 0x80000000u);
}
__device__ __forceinline__ float dec_f32(unsigned int u) {
    if (u == 0u) return 0.0f;
    return __uint_as_float((u & 0x80000000u) ? (u ^ 0x80000000u) : ~u);
}

__global__ void voxel_scatter_max(const float* __restrict__ feat,
                                  const float* __restrict__ coords,
                                  unsigned int* __restrict__ out,
                                  int BN, int N, int F) {
    int gid   = blockIdx.x * blockDim.x + threadIdx.x;
    int point = gid / (F / 4);
    int fi    = gid % (F / 4);
    if (point >= BN) return;
    int idx = cell_of(coords, point, N);
    const float4 v = *(const float4*)(feat + (size_t)point * F + fi * 4);
    unsigned int* o = out + (size_t)idx * F + fi * 4;
    atomicMax(o + 0, enc_f32(v.x));
    atomicMax(o + 1, enc_f32(v.y));
    atomicMax(o + 2, enc_f32(v.z));
    atomicMax(o + 3, enc_f32(v.w));
}

__global__ void voxel_decode(unsigned int* __restrict__ out, int n4) {
    int i = blockIdx.x * blockDim.x + threadIdx.x;
    if (i >= n4) return;
    uint4 u = ((const uint4*)out)[i];
    float4 f;
    f.x = dec_f32(u.x); f.y = dec_f32(u.y);
    f.z = dec_f32(u.z); f.w = dec_f32(u.w);
    ((float4*)out)[i] = f;
}

// ---------- launch ----------

extern "C" void kernel_launch(void* const* d_in, const int* in_sizes, int n_in,
                              void* d_out, int out_size, void* d_ws, size_t ws_size,
                              hipStream_t stream) {
    const float* feat   = (const float*)d_in[0];
    const float* coords = (const float*)d_in[1];
    float* out          = (float*)d_out;

    const int BN = in_sizes[1] / 2;             // 131072 points
    const int F  = in_sizes[0] / BN;            // 256
    const int B  = out_size / (NCELL * F);      // 16
    const int N  = BN / B;                      // 8192
    const int totc = B * NCELL;                 // 16384

    // ws layout (uint): counts[totc] | ovf_cnt[16] | ovf_list[OVF_MAX] | sorted[totc*CAP]
    const size_t ws_need = ((size_t)totc + 16 + OVF_MAX + (size_t)totc * CAP) * 4;
    const bool fast_ok = (F == 256) && (B * N == BN) && (B * NCELL * F == out_size) &&
                         (ws_size >= ws_need);

    if (fast_ok) {
        unsigned int* counts   = (unsigned int*)d_ws;
        unsigned int* ovf_cnt  = counts + totc;
        unsigned int* ovf_list = ovf_cnt + 16;
        unsigned int* sorted   = ovf_list + OVF_MAX;

        // zero counts + ovf_cnt (contiguous) via runtime fill
        hipMemsetAsync(counts, 0, (size_t)(totc + 16) * sizeof(unsigned int), stream);
        scatter_bucket<<<(BN + 255) / 256, 256, 0, stream>>>(coords, counts, sorted,
                                                             ovf_cnt, ovf_list, BN, N);
        // 2 waves per cell -> totc*2 waves, 4 waves per 256-thread block
        gather_kernel<<<totc * 2 / 4, 256, 0, stream>>>(feat, coords, sorted, counts,
                                                        ovf_cnt, ovf_list, out, N, F);
    } else {
        hipMemsetAsync(d_out, 0, (size_t)out_size * sizeof(float), stream);
        int threads = BN * (F / 4);
        voxel_scatter_max<<<(threads + 255) / 256, 256, 0, stream>>>(feat, coords,
                                                                     (unsigned int*)d_out,
                                                                     BN, N, F);
        int n4 = out_size / 4;
        voxel_decode<<<(n4 + 255) / 256, 256, 0, stream>>>((unsigned int*)d_out, n4);
    }
}